// Round 12
// baseline (74.006 us; speedup 1.0000x reference)
//
#include <hip/hip_runtime.h>
#include <hip/hip_bf16.h>

#define MM 64
#define KTOT 4096
#define NN 11008
#define PACKS 1376    // NN / 8
#define BN 128
#define NBLK 86       // NN / BN
#define KSPLIT 8
#define BKCHUNK 512   // KTOT / KSPLIT
#define BK 64         // k per step
#define NBLOCKS (NBLK * KSPLIT)  // 688
#define NREP 4        // diagnostic: x4 internal repeat so awq tops the counter table

typedef float f32x4 __attribute__((ext_vector_type(4)));
typedef short bf16x8 __attribute__((ext_vector_type(8)));

__device__ __forceinline__ unsigned int f2bf(float f) {
    unsigned int b = __float_as_uint(f);
    return (b + 0x7FFFu + ((b >> 16) & 1u)) >> 16;   // RNE to bf16
}
__device__ __forceinline__ float bf2f(unsigned int h) {
    return __uint_as_float(h << 16);
}

// prep: 256 blocks (64 m x 4 k-quarters) x 256 thr.
// xbf = bf16(x) linear [m][k]; Rbuf[g][m] = sum over group g of bf16(x[m][k]).
__global__ __launch_bounds__(256) void prep(const float* __restrict__ x,
                                            unsigned short* __restrict__ xbf,
                                            float* __restrict__ Rbuf) {
    const int m = blockIdx.x >> 2, kq = blockIdx.x & 3, t = threadIdx.x;
    const int k = kq * 1024 + t * 4;
    const float4 v = *reinterpret_cast<const float4*>(x + m * KTOT + k);
    const unsigned a = f2bf(v.x), b = f2bf(v.y), c = f2bf(v.z), d = f2bf(v.w);
    *reinterpret_cast<uint2*>(xbf + m * KTOT + k) =
        make_uint2(a | (b << 16), c | (d << 16));
    float s = bf2f(a) + bf2f(b) + bf2f(c) + bf2f(d);
    s += __shfl_xor(s, 1);
    s += __shfl_xor(s, 2);
    s += __shfl_xor(s, 4);
    s += __shfl_xor(s, 8);
    s += __shfl_xor(s, 16);                      // 32 lanes = one 128-k group
    if ((t & 31) == 0) Rbuf[(kq * 8 + (t >> 5)) * 64 + m] = s;
}

// AWQ GEMM, R10 structure, x NREP internal repeat (diagnostic).
// Reps accumulate into the same ACC (data-dependent, non-eliminable);
// store 0.25*ACC -> numerically ~= single pass (few-ulp diff).
__global__ __launch_bounds__(512, 4) void awq_mfma(
    const unsigned short* __restrict__ xbf, const int* __restrict__ qw,
    const int* __restrict__ qz, const float* __restrict__ sc,
    const float* __restrict__ Rbuf, float* __restrict__ part)
{
    __shared__ __attribute__((aligned(16))) unsigned int qt[2][16][68];  // [cp][k], pad
    __shared__ __attribute__((aligned(16))) unsigned int xst[2][64][32]; // [m][k-dw swz]

    const int tid = threadIdx.x, wv = tid >> 6, l = tid & 63;
    const int bid = blockIdx.x;
    const int ks  = bid & 7;              // k-stripe == XCD (round-robin dispatch)
    const int bn  = bid >> 3;
    const int k00 = ks * BKCHUNK;
    const int l15 = l & 15, l4 = l >> 4;

    // block-cooperative staging maps (fully coalesced)
    const int qrow = tid >> 3, qc2 = (tid & 7) * 2;   // 64 k-rows x 16 dw (64B/row)
    const int xrow = tid >> 3, xsl = tid & 7;         // 64 m-rows x 8 slots of 16B

    // compute-lane constants
    const int nloc = wv * 16 + l15;
    const int cp   = nloc >> 3;
    const int j    = nloc & 7;
    const int sh   = ((j >> 1) << 2) + ((j & 1) << 4);// AWQ nibble shift (validated)
    const int ncol = bn * BN + nloc;

    const int qstride = BK * PACKS;                   // dwords per k-step
    const int g0 = k00 >> 7;

    uint2 qreg0, qreg1;
    uint4 xreg0, xreg1;
    float s_c, szb_c, s_n = 0.f;
    int zz_n = 0;
    f32x4 accP[4], ACC[4] = {};

#define COMPUTE(B) do {                                                       \
    _Pragma("unroll")                                                         \
    for (int kk = 0; kk < 2; ++kk) {                                          \
        const int k0 = kk * 32 + l4 * 8;                                      \
        const uint4 qa = *reinterpret_cast<const uint4*>(&qt[B][cp][k0]);     \
        const uint4 qb = *reinterpret_cast<const uint4*>(&qt[B][cp][k0 + 4]); \
        uint4 db;                                                             \
        db.x = (((qa.x >> sh) & 0xFu) | (((qa.y >> sh) & 0xFu) << 16)) | 0x43004300u; \
        db.y = (((qa.z >> sh) & 0xFu) | (((qa.w >> sh) & 0xFu) << 16)) | 0x43004300u; \
        db.z = (((qb.x >> sh) & 0xFu) | (((qb.y >> sh) & 0xFu) << 16)) | 0x43004300u; \
        db.w = (((qb.z >> sh) & 0xFu) | (((qb.w >> sh) & 0xFu) << 16)) | 0x43004300u; \
        const bf16x8 bfr = __builtin_bit_cast(bf16x8, db);                    \
        _Pragma("unroll")                                                     \
        for (int mt = 0; mt < 4; ++mt) {                                      \
            const int r = mt * 16 + l15;                                      \
            const int c = (kk * 16 + l4 * 4) ^ ((r & 7) << 2);                \
            const bf16x8 af = *reinterpret_cast<const bf16x8*>(&xst[B][r][c]);\
            accP[mt] = __builtin_amdgcn_mfma_f32_16x16x32_bf16(af, bfr, accP[mt], 0, 0, 0); \
        }                                                                     \
    }                                                                         \
} while (0)

#pragma clang loop unroll(disable)
    for (int rep = 0; rep < NREP; ++rep) {
        const int* qp = qw + (k00 + qrow) * PACKS + bn * 16 + qc2;
        const unsigned short* xp = xbf + xrow * KTOT + k00 + xsl * 8;
        const float* Rg = Rbuf + g0 * 64;

        // prologue (per rep)
        qreg0 = *reinterpret_cast<const uint2*>(qp);
        xreg0 = *reinterpret_cast<const uint4*>(xp);
        s_c = sc[g0 * NN + ncol];
        {
            const int zz = qz[g0 * PACKS + (ncol >> 3)];
            szb_c = s_c * (128.0f + (float)((zz >> sh) & 0xF));
        }

#pragma clang loop unroll(disable)
        for (int it = 0; it < 4; ++it) {
            // ======== phase 0 (even step, buffer 0) ========
            qreg1 = *reinterpret_cast<const uint2*>(qp + qstride);   // in-bounds always
            xreg1 = *reinterpret_cast<const uint4*>(xp + BK);
            accP[0] = (f32x4){};
            accP[1] = (f32x4){};
            accP[2] = (f32x4){};
            accP[3] = (f32x4){};
            if (it < 3) {   // next group's scale/zero
                s_n  = sc[(g0 + it + 1) * NN + ncol];
                zz_n = qz[(g0 + it + 1) * PACKS + (ncol >> 3)];
            }
            qt[0][qc2][qrow]     = qreg0.x;
            qt[0][qc2 + 1][qrow] = qreg0.y;
            *reinterpret_cast<uint4*>(&xst[0][xrow][(xsl ^ (xrow & 7)) << 2]) = xreg0;
            asm volatile("s_waitcnt lgkmcnt(0)\n\ts_barrier" ::: "memory");
            COMPUTE(0);

            // ======== phase 1 (odd step, buffer 1) ========
            if (it < 3) {   // prefetch next even step (guarded: OOB at it=3)
                qreg0 = *reinterpret_cast<const uint2*>(qp + 2 * qstride);
                xreg0 = *reinterpret_cast<const uint4*>(xp + 2 * BK);
            }
            qt[1][qc2][qrow]     = qreg1.x;
            qt[1][qc2 + 1][qrow] = qreg1.y;
            *reinterpret_cast<uint4*>(&xst[1][xrow][(xsl ^ (xrow & 7)) << 2]) = xreg1;
            asm volatile("s_waitcnt lgkmcnt(0)\n\ts_barrier" ::: "memory");
            COMPUTE(1);

            // ---- group end: ACC += s*P - s*(128+z)*R ----
#pragma unroll
            for (int mt = 0; mt < 4; ++mt) {
                const float4 r4 = *reinterpret_cast<const float4*>(Rg + mt * 16 + l4 * 4);
                const float rr[4] = { r4.x, r4.y, r4.z, r4.w };
#pragma unroll
                for (int r = 0; r < 4; ++r) {
                    ACC[mt][r] = fmaf(s_c, accP[mt][r], ACC[mt][r]);
                    ACC[mt][r] = fmaf(-szb_c, rr[r], ACC[mt][r]);
                }
            }
            s_c   = s_n;    // stale at it=3, unused
            szb_c = s_n * (128.0f + (float)((zz_n >> sh) & 0xF));

            qp += 2 * qstride;
            xp += 2 * BK;
            Rg += 64;
        }
    }
#undef COMPUTE

    // ---- epilogue: stores of ACC/NREP (C/D: col=lane&15, row=(lane>>4)*4+r) ----
    float* pout = part + ks * (MM * NN) + bn * BN + wv * 16;
#pragma unroll
    for (int mt = 0; mt < 4; ++mt) {
        const int r0 = mt * 16 + l4 * 4;
#pragma unroll
        for (int r = 0; r < 4; ++r)
            pout[(r0 + r) * NN + l15] = 0.25f * ACC[mt][r];
    }
}

// reduce: out = bias + sum_ks part[ks]
__global__ __launch_bounds__(256) void reduce_k(const float* __restrict__ part,
                                                const float* __restrict__ bias,
                                                float* __restrict__ out) {
    const int t = blockIdx.x * 256 + threadIdx.x;   // float4 idx, 176128 total
    const int n = (t * 4) % NN;
    float4 s = reinterpret_cast<const float4*>(part)[t];
#pragma unroll
    for (int ks = 1; ks < KSPLIT; ++ks) {
        const float4 v = reinterpret_cast<const float4*>(part + ks * (MM * NN))[t];
        s.x += v.x; s.y += v.y; s.z += v.z; s.w += v.w;
    }
    const float4 b = *reinterpret_cast<const float4*>(bias + n);
    s.x += b.x; s.y += b.y; s.z += b.z; s.w += b.w;
    reinterpret_cast<float4*>(out)[t] = s;
}

extern "C" void kernel_launch(void* const* d_in, const int* in_sizes, int n_in,
                              void* d_out, int out_size, void* d_ws, size_t ws_size,
                              hipStream_t stream) {
    const float* x    = (const float*)d_in[0];
    const int*   qw   = (const int*)d_in[1];
    const int*   qz   = (const int*)d_in[2];
    const float* sc   = (const float*)d_in[3];
    const float* bias = (const float*)d_in[4];
    float* out = (float*)d_out;

    unsigned short* xbf = (unsigned short*)d_ws;                              // 512 KB
    float* Rbuf = (float*)((char*)d_ws + MM * KTOT * sizeof(unsigned short)); // 8 KB
    float* part = (float*)((char*)d_ws + MM * KTOT * sizeof(unsigned short)
                           + 32 * 64 * sizeof(float));                        // 22.5 MB

    prep<<<dim3(256), 256, 0, stream>>>(x, xbf, Rbuf);
    awq_mfma<<<dim3(NBLOCKS), 512, 0, stream>>>(xbf, qw, qz, sc, Rbuf, part);
    reduce_k<<<dim3(MM * NN / 4 / 256), 256, 0, stream>>>(part, bias, out);
}

// Round 13
// 37.517 us; speedup vs baseline: 1.9726x; 1.9726x over previous
//
#include <hip/hip_runtime.h>
#include <hip/hip_bf16.h>

#define MM 64
#define KTOT 4096
#define NN 11008
#define PACKS 1376    // NN / 8
#define BN 128
#define NBLK 86       // NN / BN
#define KSPLIT 8
#define BKCHUNK 512   // KTOT / KSPLIT
#define BK 64         // k per step
#define NBLOCKS (NBLK * KSPLIT)  // 688

typedef float f32x4 __attribute__((ext_vector_type(4)));
typedef short bf16x8 __attribute__((ext_vector_type(8)));

__device__ __forceinline__ unsigned int f2bf(float f) {
    unsigned int b = __float_as_uint(f);
    return (b + 0x7FFFu + ((b >> 16) & 1u)) >> 16;   // RNE to bf16
}
__device__ __forceinline__ float bf2f(unsigned int h) {
    return __uint_as_float(h << 16);
}

// prep: 256 blocks (64 m x 4 k-quarters) x 256 thr.
// xbf = bf16(x) linear [m][k]; Rbuf[g][m] = sum over group g of bf16(x[m][k]).
__global__ __launch_bounds__(256) void prep(const float* __restrict__ x,
                                            unsigned short* __restrict__ xbf,
                                            float* __restrict__ Rbuf) {
    const int m = blockIdx.x >> 2, kq = blockIdx.x & 3, t = threadIdx.x;
    const int k = kq * 1024 + t * 4;
    const float4 v = *reinterpret_cast<const float4*>(x + m * KTOT + k);
    const unsigned a = f2bf(v.x), b = f2bf(v.y), c = f2bf(v.z), d = f2bf(v.w);
    *reinterpret_cast<uint2*>(xbf + m * KTOT + k) =
        make_uint2(a | (b << 16), c | (d << 16));
    float s = bf2f(a) + bf2f(b) + bf2f(c) + bf2f(d);
    s += __shfl_xor(s, 1);
    s += __shfl_xor(s, 2);
    s += __shfl_xor(s, 4);
    s += __shfl_xor(s, 8);
    s += __shfl_xor(s, 16);                      // 32 lanes = one 128-k group
    if ((t & 31) == 0) Rbuf[(kq * 8 + (t >> 5)) * 64 + m] = s;
}

// AWQ GEMM: 256 thr / 4 waves, wave = 64m x 32n (WN=32 halves the A-tile
// LDS re-read redundancy vs WN=16). Rolled K-loop, 2-step-deep staging
// prefetch ring, bias-trick B-build, group correction ACC += s*P - s*(128+z)*R.
__global__ __launch_bounds__(256, 4) void awq_mfma(
    const unsigned short* __restrict__ xbf, const int* __restrict__ qw,
    const int* __restrict__ qz, const float* __restrict__ sc,
    const float* __restrict__ Rbuf, float* __restrict__ part)
{
    __shared__ __attribute__((aligned(16))) unsigned int qt[2][16][68];  // [cp][k], pad
    __shared__ __attribute__((aligned(16))) unsigned int xst[2][64][32]; // [m][k-dw swz]

    const int tid = threadIdx.x, wv = tid >> 6, l = tid & 63;
    const int bid = blockIdx.x;
    const int ks  = bid & 7;              // k-stripe == XCD (round-robin dispatch)
    const int bn  = bid >> 3;
    const int k00 = ks * BKCHUNK;
    const int l15 = l & 15, l4 = l >> 4;

    // block-cooperative staging maps (fully coalesced)
    const int qrow = tid >> 2, qc4 = (tid & 3) * 4;   // 64 k-rows x 16 dw (uint4/thread)
    const int xrow = tid >> 2, xs0 = tid & 3;         // 64 m-rows, slots xs0 and xs0+4

    // compute-lane constants (wave owns n in [wv*32, wv*32+32): nt=0,1 halves)
    const int j    = l15 & 7;
    const int sh   = ((j >> 1) << 2) + ((j & 1) << 4);// AWQ nibble shift (validated)
    const int cp0  = wv * 4 + (l15 >> 3);             // pack-col for nt=0
    const int cp1  = cp0 + 2;                         // pack-col for nt=1
    const int ncol0 = bn * BN + wv * 32 + l15;
    const int ncol1 = ncol0 + 16;

    const int qstride = BK * PACKS;
    const int* qp = qw + (k00 + qrow) * PACKS + bn * 16 + qc4;
    const unsigned short* xp = xbf + xrow * KTOT + k00 + xs0 * 8;
    const int g0 = k00 >> 7;
    const float* Rg = Rbuf + g0 * 64;

    uint4 qA, qB, xA0, xA1, xB0, xB1;   // 2-step-deep staging ring
    float s_c0, s_c1, szb0, szb1, s_n0 = 0.f, s_n1 = 0.f;
    int zzn0 = 0, zzn1 = 0;
    f32x4 accP[4][2], ACC[4][2] = {};

    // prologue: steps 0 and 1 staged into the ring + group-0 scale/zero
    qA  = *reinterpret_cast<const uint4*>(qp);
    xA0 = *reinterpret_cast<const uint4*>(xp);
    xA1 = *reinterpret_cast<const uint4*>(xp + 32);
    qB  = *reinterpret_cast<const uint4*>(qp + qstride);
    xB0 = *reinterpret_cast<const uint4*>(xp + BK);
    xB1 = *reinterpret_cast<const uint4*>(xp + BK + 32);
    s_c0 = sc[g0 * NN + ncol0];
    s_c1 = sc[g0 * NN + ncol1];
    {
        const int z0 = qz[g0 * PACKS + (ncol0 >> 3)];
        const int z1 = qz[g0 * PACKS + (ncol1 >> 3)];
        szb0 = s_c0 * (128.0f + (float)((z0 >> sh) & 0xF));
        szb1 = s_c1 * (128.0f + (float)((z1 >> sh) & 0xF));
    }

#define BBUILD(QA, QB, DST) do {                                              \
    uint4 db_;                                                                \
    db_.x = (((QA.x >> sh) & 0xFu) | (((QA.y >> sh) & 0xFu) << 16)) | 0x43004300u; \
    db_.y = (((QA.z >> sh) & 0xFu) | (((QA.w >> sh) & 0xFu) << 16)) | 0x43004300u; \
    db_.z = (((QB.x >> sh) & 0xFu) | (((QB.y >> sh) & 0xFu) << 16)) | 0x43004300u; \
    db_.w = (((QB.z >> sh) & 0xFu) | (((QB.w >> sh) & 0xFu) << 16)) | 0x43004300u; \
    DST = __builtin_bit_cast(bf16x8, db_);                                    \
} while (0)

#define COMPUTE(B) do {                                                       \
    _Pragma("unroll")                                                         \
    for (int kk = 0; kk < 2; ++kk) {                                          \
        const int k0 = kk * 32 + l4 * 8;                                      \
        const uint4 qa0 = *reinterpret_cast<const uint4*>(&qt[B][cp0][k0]);   \
        const uint4 qb0 = *reinterpret_cast<const uint4*>(&qt[B][cp0][k0 + 4]); \
        const uint4 qa1 = *reinterpret_cast<const uint4*>(&qt[B][cp1][k0]);   \
        const uint4 qb1 = *reinterpret_cast<const uint4*>(&qt[B][cp1][k0 + 4]); \
        bf16x8 bfr0, bfr1;                                                    \
        BBUILD(qa0, qb0, bfr0);                                               \
        BBUILD(qa1, qb1, bfr1);                                               \
        _Pragma("unroll")                                                     \
        for (int mt = 0; mt < 4; ++mt) {                                      \
            const int r = mt * 16 + l15;                                      \
            const int c = (kk * 16 + l4 * 4) ^ ((r & 7) << 2);                \
            const bf16x8 af = *reinterpret_cast<const bf16x8*>(&xst[B][r][c]);\
            accP[mt][0] = __builtin_amdgcn_mfma_f32_16x16x32_bf16(af, bfr0, accP[mt][0], 0, 0, 0); \
            accP[mt][1] = __builtin_amdgcn_mfma_f32_16x16x32_bf16(af, bfr1, accP[mt][1], 0, 0, 0); \
        }                                                                     \
    }                                                                         \
} while (0)

#pragma clang loop unroll(disable)
    for (int it = 0; it < 4; ++it) {
        // ======== phase 0 (even step, buffer 0) ========
        qt[0][qc4    ][qrow] = qA.x;
        qt[0][qc4 + 1][qrow] = qA.y;
        qt[0][qc4 + 2][qrow] = qA.z;
        qt[0][qc4 + 3][qrow] = qA.w;
        *reinterpret_cast<uint4*>(&xst[0][xrow][(xs0 ^ (xrow & 7)) << 2]) = xA0;
        *reinterpret_cast<uint4*>(&xst[0][xrow][((xs0 + 4) ^ (xrow & 7)) << 2]) = xA1;
        if (it < 3) {   // refill ring 2 steps ahead (covers L2-miss latency)
            qA  = *reinterpret_cast<const uint4*>(qp + 2 * qstride);
            xA0 = *reinterpret_cast<const uint4*>(xp + 2 * BK);
            xA1 = *reinterpret_cast<const uint4*>(xp + 2 * BK + 32);
            s_n0 = sc[(g0 + it + 1) * NN + ncol0];
            s_n1 = sc[(g0 + it + 1) * NN + ncol1];
            zzn0 = qz[(g0 + it + 1) * PACKS + (ncol0 >> 3)];
            zzn1 = qz[(g0 + it + 1) * PACKS + (ncol1 >> 3)];
        }
#pragma unroll
        for (int mt = 0; mt < 4; ++mt) {
            accP[mt][0] = (f32x4){};
            accP[mt][1] = (f32x4){};
        }
        asm volatile("s_waitcnt lgkmcnt(0)\n\ts_barrier" ::: "memory");
        COMPUTE(0);

        // ======== phase 1 (odd step, buffer 1) ========
        qt[1][qc4    ][qrow] = qB.x;
        qt[1][qc4 + 1][qrow] = qB.y;
        qt[1][qc4 + 2][qrow] = qB.z;
        qt[1][qc4 + 3][qrow] = qB.w;
        *reinterpret_cast<uint4*>(&xst[1][xrow][(xs0 ^ (xrow & 7)) << 2]) = xB0;
        *reinterpret_cast<uint4*>(&xst[1][xrow][((xs0 + 4) ^ (xrow & 7)) << 2]) = xB1;
        if (it < 3) {
            qB  = *reinterpret_cast<const uint4*>(qp + 3 * qstride);
            xB0 = *reinterpret_cast<const uint4*>(xp + 3 * BK);
            xB1 = *reinterpret_cast<const uint4*>(xp + 3 * BK + 32);
        }
        asm volatile("s_waitcnt lgkmcnt(0)\n\ts_barrier" ::: "memory");
        COMPUTE(1);

        // ---- group end: ACC += s*P - s*(128+z)*R (R shared across nt) ----
#pragma unroll
        for (int mt = 0; mt < 4; ++mt) {
            const float4 r4 = *reinterpret_cast<const float4*>(Rg + mt * 16 + l4 * 4);
            const float rr[4] = { r4.x, r4.y, r4.z, r4.w };
#pragma unroll
            for (int r = 0; r < 4; ++r) {
                ACC[mt][0][r] = fmaf(s_c0, accP[mt][0][r], ACC[mt][0][r]);
                ACC[mt][0][r] = fmaf(-szb0, rr[r], ACC[mt][0][r]);
                ACC[mt][1][r] = fmaf(s_c1, accP[mt][1][r], ACC[mt][1][r]);
                ACC[mt][1][r] = fmaf(-szb1, rr[r], ACC[mt][1][r]);
            }
        }
        s_c0 = s_n0;    // stale at it=3, unused
        s_c1 = s_n1;
        szb0 = s_n0 * (128.0f + (float)((zzn0 >> sh) & 0xF));
        szb1 = s_n1 * (128.0f + (float)((zzn1 >> sh) & 0xF));

        qp += 2 * qstride;
        xp += 2 * BK;
        Rg += 64;
    }
#undef COMPUTE
#undef BBUILD

    // ---- epilogue: plain stores (C/D: col=lane&15, row=(lane>>4)*4+r) ----
    float* pout = part + ks * (MM * NN) + bn * BN + wv * 32;
#pragma unroll
    for (int mt = 0; mt < 4; ++mt) {
        const int r0 = mt * 16 + l4 * 4;
#pragma unroll
        for (int r = 0; r < 4; ++r) {
            pout[(r0 + r) * NN + l15]      = ACC[mt][0][r];
            pout[(r0 + r) * NN + 16 + l15] = ACC[mt][1][r];
        }
    }
}

// reduce: out = bias + sum_ks part[ks]
__global__ __launch_bounds__(256) void reduce_k(const float* __restrict__ part,
                                                const float* __restrict__ bias,
                                                float* __restrict__ out) {
    const int t = blockIdx.x * 256 + threadIdx.x;   // float4 idx, 176128 total
    const int n = (t * 4) % NN;
    float4 s = reinterpret_cast<const float4*>(part)[t];
#pragma unroll
    for (int ks = 1; ks < KSPLIT; ++ks) {
        const float4 v = reinterpret_cast<const float4*>(part + ks * (MM * NN))[t];
        s.x += v.x; s.y += v.y; s.z += v.z; s.w += v.w;
    }
    const float4 b = *reinterpret_cast<const float4*>(bias + n);
    s.x += b.x; s.y += b.y; s.z += b.z; s.w += b.w;
    reinterpret_cast<float4*>(out)[t] = s;
}

extern "C" void kernel_launch(void* const* d_in, const int* in_sizes, int n_in,
                              void* d_out, int out_size, void* d_ws, size_t ws_size,
                              hipStream_t stream) {
    const float* x    = (const float*)d_in[0];
    const int*   qw   = (const int*)d_in[1];
    const int*   qz   = (const int*)d_in[2];
    const float* sc   = (const float*)d_in[3];
    const float* bias = (const float*)d_in[4];
    float* out = (float*)d_out;

    unsigned short* xbf = (unsigned short*)d_ws;                              // 512 KB
    float* Rbuf = (float*)((char*)d_ws + MM * KTOT * sizeof(unsigned short)); // 8 KB
    float* part = (float*)((char*)d_ws + MM * KTOT * sizeof(unsigned short)
                           + 32 * 64 * sizeof(float));                        // 22.5 MB

    prep<<<dim3(256), 256, 0, stream>>>(x, xbf, Rbuf);
    awq_mfma<<<dim3(NBLOCKS), 256, 0, stream>>>(xbf, qw, qz, sc, Rbuf, part);
    reduce_k<<<dim3(MM * NN / 4 / 256), 256, 0, stream>>>(part, bias, out);
}